// Round 5
// baseline (173.281 us; speedup 1.0000x reference)
//
#include <hip/hip_runtime.h>

#define B_ROWS 2048
#define S_LEN 8192
#define SEG_OUT 1024
#define WARM 512
#define EXT (SEG_OUT + WARM)            // 1536
#define CHUNK 8                         // elems per lane per tile
#define TILE (64 * CHUNK)               // 512
#define NTILE (EXT / TILE)              // 3
#define NSEG (S_LEN / SEG_OUT)          // 8
#define WPB 4
#define NBLOCKS (B_ROWS * NSEG / WPB)   // 4096

// ---- compile-time decay constants for chunk=8 scan, trimmed below 1e-8 ----
constexpr double cpowi(double b, int e) { double r = 1.0; for (int i = 0; i < e; ++i) r *= b; return r; }
constexpr float trim(double x) { return (x < 1e-8 && x > -1e-8) ? 0.0f : (float)x; }

#define A0f 0.1f
#define A1f 0.3f
#define A2f 0.6f

// step s uses (1-alpha)^(CHUNK * s), s = 1,2,4,8,16,32
constexpr float E0_1 = trim(cpowi(0.9, 8)),   E0_2 = trim(cpowi(0.9, 16)),  E0_4 = trim(cpowi(0.9, 32));
constexpr float E0_8 = trim(cpowi(0.9, 64)),  E0_16 = trim(cpowi(0.9, 128)), E0_32 = trim(cpowi(0.9, 256));
constexpr float E1_1 = trim(cpowi(0.7, 8)),   E1_2 = trim(cpowi(0.7, 16)),  E1_4 = trim(cpowi(0.7, 32));
constexpr float E1_8 = trim(cpowi(0.7, 64)),  E1_16 = trim(cpowi(0.7, 128)), E1_32 = trim(cpowi(0.7, 256));
constexpr float E2_1 = trim(cpowi(0.4, 8)),   E2_2 = trim(cpowi(0.4, 16)),  E2_4 = trim(cpowi(0.4, 32));
constexpr float E2_8 = trim(cpowi(0.4, 64)),  E2_16 = trim(cpowi(0.4, 128)), E2_32 = trim(cpowi(0.4, 256));

__device__ __forceinline__ float ema_scan(float v, int lane,
                                          float d1, float d2, float d4,
                                          float d8, float d16, float d32) {
    float u;
    if (d1 != 0.0f) { u = __shfl_up(v, 1);  v += (lane >= 1  ? d1  : 0.0f) * u; }
    if (d2 != 0.0f) { u = __shfl_up(v, 2);  v += (lane >= 2  ? d2  : 0.0f) * u; }
    if (d4 != 0.0f) { u = __shfl_up(v, 4);  v += (lane >= 4  ? d4  : 0.0f) * u; }
    if (d8 != 0.0f) { u = __shfl_up(v, 8);  v += (lane >= 8  ? d8  : 0.0f) * u; }
    if (d16 != 0.0f) { u = __shfl_up(v, 16); v += (lane >= 16 ? d16 : 0.0f) * u; }
    if (d32 != 0.0f) { u = __shfl_up(v, 32); v += (lane >= 32 ? d32 : 0.0f) * u; }
    return v;
}

__device__ __forceinline__ float huber(float pd, float td) {
    float dir = pd * td;
    float se  = fabsf(pd - td);
    float mm  = fmaxf(1.0f - dir, 0.0f);
    float q   = 0.5f * mm * mm;
    return dir < 0.0f ? se : q;
}

#define PASS1(px, tx)                                         \
    Lp0 += A0f * ((px) - Lp0); Lp1 += A1f * ((px) - Lp1);     \
    Lp2 += A2f * ((px) - Lp2);                                \
    Lt0 += A0f * ((tx) - Lt0); Lt1 += A1f * ((tx) - Lt1);     \
    Lt2 += A2f * ((tx) - Lt2);

#define PASS2(px, tx, J) {                                    \
    float pd0 = A0f * ((px) - yp0); yp0 += pd0;               \
    float td0 = A0f * ((tx) - yt0); yt0 += td0;               \
    float pd1 = A1f * ((px) - yp1); yp1 += pd1;               \
    float td1 = A1f * ((tx) - yt1); yt1 += td1;               \
    float pd2 = A2f * ((px) - yp2); yp2 += pd2;               \
    float td2 = A2f * ((tx) - yt2); yt2 += td2;               \
    const float m_ = ((ebase + (J)) >= lo) ? 1.0f : 0.0f;     \
    acc0 += m_ * huber(pd0, td0);                             \
    acc1 += m_ * huber(pd1, td1);                             \
    acc2 += m_ * huber(pd2, td2); }

// One tile: 8 elems/lane, load->pass1->scan->carry->pass2, everything live
// for only this tile (max 4 float4 of x per array => no spill pressure).
__device__ __forceinline__ void do_tile(
    float4 A0, float4 A1, float4 B0, float4 B1,
    int lane, bool lz, int ebase, int lo, bool run2,
    float& sp0, float& sp1, float& sp2,
    float& st0, float& st1, float& st2,
    float& acc0, float& acc1, float& acc2)
{
    // ---- pass 1: lane-local EMA, carry-in only on lane 0 ----
    float Lp0 = lz ? sp0 : 0.f, Lp1 = lz ? sp1 : 0.f, Lp2 = lz ? sp2 : 0.f;
    float Lt0 = lz ? st0 : 0.f, Lt1 = lz ? st1 : 0.f, Lt2 = lz ? st2 : 0.f;
    PASS1(A0.x, B0.x) PASS1(A0.y, B0.y) PASS1(A0.z, B0.z) PASS1(A0.w, B0.w)
    PASS1(A1.x, B1.x) PASS1(A1.y, B1.y) PASS1(A1.z, B1.z) PASS1(A1.w, B1.w)

    // ---- wave scan (chunk-8 decay constants) ----
    float vp0 = ema_scan(Lp0, lane, E0_1, E0_2, E0_4, E0_8, E0_16, E0_32);
    float vp1 = ema_scan(Lp1, lane, E1_1, E1_2, E1_4, E1_8, E1_16, E1_32);
    float vp2 = ema_scan(Lp2, lane, E2_1, E2_2, E2_4, E2_8, E2_16, E2_32);
    float vt0 = ema_scan(Lt0, lane, E0_1, E0_2, E0_4, E0_8, E0_16, E0_32);
    float vt1 = ema_scan(Lt1, lane, E1_1, E1_2, E1_4, E1_8, E1_16, E1_32);
    float vt2 = ema_scan(Lt2, lane, E2_1, E2_2, E2_4, E2_8, E2_16, E2_32);

    // exclusive carry = EMA state just before this lane's chunk
    float yp0 = lz ? sp0 : __shfl_up(vp0, 1);
    float yp1 = lz ? sp1 : __shfl_up(vp1, 1);
    float yp2 = lz ? sp2 : __shfl_up(vp2, 1);
    float yt0 = lz ? st0 : __shfl_up(vt0, 1);
    float yt1 = lz ? st1 : __shfl_up(vt1, 1);
    float yt2 = lz ? st2 : __shfl_up(vt2, 1);

    // carry out for next tile (state at end of this tile)
    sp0 = __shfl(vp0, 63); sp1 = __shfl(vp1, 63); sp2 = __shfl(vp2, 63);
    st0 = __shfl(vt0, 63); st1 = __shfl(vt1, 63); st2 = __shfl(vt2, 63);

    if (run2) {  // wave-uniform: skip pure-warmup / pure-overhang tiles
        PASS2(A0.x, B0.x, 0) PASS2(A0.y, B0.y, 1) PASS2(A0.z, B0.z, 2) PASS2(A0.w, B0.w, 3)
        PASS2(A1.x, B1.x, 4) PASS2(A1.y, B1.y, 5) PASS2(A1.z, B1.z, 6) PASS2(A1.w, B1.w, 7)
    }
}

__global__ void __launch_bounds__(256, 5) msl_main(const float* __restrict__ pred,
                                                   const float* __restrict__ targ,
                                                   float* __restrict__ out) {
    const int lane = threadIdx.x & 63;
    const int wave = threadIdx.x >> 6;
    const int g    = blockIdx.x * WPB + wave;   // global wave id
    const int row  = g >> 3;                    // NSEG = 8
    const int seg  = g & 7;
    const bool s0  = (seg == 0);
    const bool lz  = (lane == 0);

    // seg s covers ext [s*1024-512, s*1024+1024) (s0: [0,1536)).
    // s0: outputs e in [1,1024) -> tiles 0,1 run pass2 (lo=1), tile2 skipped.
    // s>0: tile0 = pure warmup (zero IC, (1-a)^512 -> exact), tiles 1,2 output.
    const int ext_base = s0 ? 0 : seg * SEG_OUT - WARM;
    const int lo = s0 ? 1 : WARM;

    const float* __restrict__ prow = pred + (size_t)row * S_LEN + ext_base;
    const float* __restrict__ trow = targ + (size_t)row * S_LEN + ext_base;
    const float4* p4 = reinterpret_cast<const float4*>(prow);
    const float4* t4 = reinterpret_cast<const float4*>(trow);
    const int fo = lane * 2;                    // float4 index of lane within tile

    // EMA carry state (value at end of previous tile); zero start,
    // except s0 gets the exact pe[0]=x[0] initial condition on lane 0.
    float sp0 = 0.f, sp1 = 0.f, sp2 = 0.f, st0 = 0.f, st1 = 0.f, st2 = 0.f;
    float acc0 = 0.f, acc1 = 0.f, acc2 = 0.f;

    // tile 0 load
    float4 A0 = p4[fo], A1 = p4[fo + 1];
    float4 B0 = t4[fo], B1 = t4[fo + 1];
    // prefetch tile 1
    float4 nA0 = p4[128 + fo], nA1 = p4[128 + fo + 1];
    float4 nB0 = t4[128 + fo], nB1 = t4[128 + fo + 1];

    if (s0 && lz) { sp0 = sp1 = sp2 = A0.x; st0 = st1 = st2 = B0.x; }

    do_tile(A0, A1, B0, B1, lane, lz, lane * CHUNK, lo, s0,
            sp0, sp1, sp2, st0, st1, st2, acc0, acc1, acc2);

    A0 = nA0; A1 = nA1; B0 = nB0; B1 = nB1;
    // prefetch tile 2
    nA0 = p4[256 + fo]; nA1 = p4[256 + fo + 1];
    nB0 = t4[256 + fo]; nB1 = t4[256 + fo + 1];

    do_tile(A0, A1, B0, B1, lane, lz, TILE + lane * CHUNK, lo, true,
            sp0, sp1, sp2, st0, st1, st2, acc0, acc1, acc2);

    do_tile(nA0, nA1, nB0, nB1, lane, lz, 2 * TILE + lane * CHUNK, lo, !s0,
            sp0, sp1, sp2, st0, st1, st2, acc0, acc1, acc2);

    // weight scales, reduce wave -> block -> global atomic
    float wacc = 0.5f * acc0 + 0.3f * acc1 + 0.2f * acc2;
#pragma unroll
    for (int o = 32; o > 0; o >>= 1) wacc += __shfl_down(wacc, o);

    __shared__ float sred[WPB];
    if (lz) sred[wave] = wacc;
    __syncthreads();
    if (threadIdx.x == 0) {
        const float scale = (float)(1.0 / ((double)(S_LEN - 1) * (double)B_ROWS));
        atomicAdd(out, (sred[0] + sred[1] + sred[2] + sred[3]) * scale);
    }
}

extern "C" void kernel_launch(void* const* d_in, const int* in_sizes, int n_in,
                              void* d_out, int out_size, void* d_ws, size_t ws_size,
                              hipStream_t stream) {
    const float* pred = (const float*)d_in[0];
    const float* targ = (const float*)d_in[1];
    float* out = (float*)d_out;

    hipMemsetAsync(out, 0, sizeof(float), stream);
    msl_main<<<NBLOCKS, 256, 0, stream>>>(pred, targ, out);
}

// Round 6
// 169.257 us; speedup vs baseline: 1.0238x; 1.0238x over previous
//
#include <hip/hip_runtime.h>

#define B_ROWS 2048
#define S_LEN 8192
#define PER_LANE 32
#define TILE_ELEMS (64 * PER_LANE)   // 2048
#define NTILES (S_LEN / TILE_ELEMS)  // 4
#define WPB 4                        // waves (rows) per block
#define NBLOCKS (B_ROWS / WPB)       // 512

// ---- compile-time decay constants, trimmed below 1e-12 ----
constexpr double cpowi(double b, int e) { double r = 1.0; for (int i = 0; i < e; ++i) r *= b; return r; }
constexpr float trim(double x) { return (x < 1e-12 && x > -1e-12) ? 0.0f : (float)x; }

#define A0f 0.1f
#define A1f 0.3f
#define A2f 0.6f

// d_k = (1-alpha)^(PER_LANE * 2^k); alpha=0.6 forgets within one 32-chunk (all 0),
// alpha=0.3 needs 2 scan steps, alpha=0.1 needs 4.
constexpr float D0_1 = trim(cpowi(0.9, 32)),  D0_2 = trim(cpowi(0.9, 64)),  D0_4 = trim(cpowi(0.9, 128));
constexpr float D0_8 = trim(cpowi(0.9, 256)), D0_16 = trim(cpowi(0.9, 512)), D0_32 = trim(cpowi(0.9, 1024));
constexpr float D1_1 = trim(cpowi(0.7, 32)),  D1_2 = trim(cpowi(0.7, 64)),  D1_4 = trim(cpowi(0.7, 128));
constexpr float D1_8 = trim(cpowi(0.7, 256)), D1_16 = trim(cpowi(0.7, 512)), D1_32 = trim(cpowi(0.7, 1024));
constexpr float D2_1 = trim(cpowi(0.4, 32)),  D2_2 = trim(cpowi(0.4, 64)),  D2_4 = trim(cpowi(0.4, 128));
constexpr float D2_8 = trim(cpowi(0.4, 256)), D2_16 = trim(cpowi(0.4, 512)), D2_32 = trim(cpowi(0.4, 1024));

// Kogge-Stone scan for the linear recurrence; compile-time-zero steps elided.
__device__ __forceinline__ float ema_scan(float v, int lane,
                                          float d1, float d2, float d4,
                                          float d8, float d16, float d32) {
    float u;
    if (d1 != 0.0f) { u = __shfl_up(v, 1);  v += (lane >= 1  ? d1  : 0.0f) * u; }
    if (d2 != 0.0f) { u = __shfl_up(v, 2);  v += (lane >= 2  ? d2  : 0.0f) * u; }
    if (d4 != 0.0f) { u = __shfl_up(v, 4);  v += (lane >= 4  ? d4  : 0.0f) * u; }
    if (d8 != 0.0f) { u = __shfl_up(v, 8);  v += (lane >= 8  ? d8  : 0.0f) * u; }
    if (d16 != 0.0f) { u = __shfl_up(v, 16); v += (lane >= 16 ? d16 : 0.0f) * u; }
    if (d32 != 0.0f) { u = __shfl_up(v, 32); v += (lane >= 32 ? d32 : 0.0f) * u; }
    return v;
}

__device__ __forceinline__ float huber(float pd, float td) {
    float dir = pd * td;
    float se  = fabsf(pd - td);
    float mm  = fmaxf(1.0f - dir, 0.0f);
    float q   = 0.5f * mm * mm;
    return dir < 0.0f ? se : q;
}

// Load tile T of this row into register arrays XP/XT (8 float4 per array).
#define LOADT(T, XP, XT) {                                                     \
    const float4* p4_ = reinterpret_cast<const float4*>(prow + (T) * TILE_ELEMS); \
    const float4* t4_ = reinterpret_cast<const float4*>(trow + (T) * TILE_ELEMS); \
    _Pragma("unroll")                                                          \
    for (int j = 0; j < PER_LANE / 4; ++j) {                                   \
        float4 a_ = p4_[fo + j]; float4 b_ = t4_[fo + j];                      \
        XP[4*j+0] = a_.x; XP[4*j+1] = a_.y; XP[4*j+2] = a_.z; XP[4*j+3] = a_.w; \
        XT[4*j+0] = b_.x; XT[4*j+1] = b_.y; XT[4*j+2] = b_.z; XT[4*j+3] = b_.w; } }

// Full tile pipeline on register-resident XP/XT. FIRST is a compile-time 0/1.
#define COMPUTE(XP, XT, FIRST) {                                               \
    float Lp0, Lp1, Lp2, Lt0, Lt1, Lt2;                                        \
    if (FIRST) {                                                               \
        const float icp_ = lz ? XP[0] : 0.0f;                                  \
        const float ict_ = lz ? XT[0] : 0.0f;                                  \
        Lp0 = Lp1 = Lp2 = icp_; Lt0 = Lt1 = Lt2 = ict_;                        \
    } else {                                                                   \
        Lp0 = lz ? sp0 : 0.f; Lp1 = lz ? sp1 : 0.f; Lp2 = lz ? sp2 : 0.f;      \
        Lt0 = lz ? st0 : 0.f; Lt1 = lz ? st1 : 0.f; Lt2 = lz ? st2 : 0.f;      \
    }                                                                          \
    _Pragma("unroll")                                                          \
    for (int j = 0; j < PER_LANE; ++j) {                                       \
        Lp0 += A0f * (XP[j] - Lp0); Lp1 += A1f * (XP[j] - Lp1);                \
        Lp2 += A2f * (XP[j] - Lp2);                                            \
        Lt0 += A0f * (XT[j] - Lt0); Lt1 += A1f * (XT[j] - Lt1);                \
        Lt2 += A2f * (XT[j] - Lt2);                                            \
    }                                                                          \
    float vp0 = ema_scan(Lp0, lane, D0_1, D0_2, D0_4, D0_8, D0_16, D0_32);     \
    float vp1 = ema_scan(Lp1, lane, D1_1, D1_2, D1_4, D1_8, D1_16, D1_32);     \
    float vp2 = ema_scan(Lp2, lane, D2_1, D2_2, D2_4, D2_8, D2_16, D2_32);     \
    float vt0 = ema_scan(Lt0, lane, D0_1, D0_2, D0_4, D0_8, D0_16, D0_32);     \
    float vt1 = ema_scan(Lt1, lane, D1_1, D1_2, D1_4, D1_8, D1_16, D1_32);     \
    float vt2 = ema_scan(Lt2, lane, D2_1, D2_2, D2_4, D2_8, D2_16, D2_32);     \
    float yp0, yp1, yp2, yt0, yt1, yt2;                                        \
    {                                                                          \
        float cp0 = __shfl_up(vp0, 1), cp1 = __shfl_up(vp1, 1), cp2 = __shfl_up(vp2, 1); \
        float ct0 = __shfl_up(vt0, 1), ct1 = __shfl_up(vt1, 1), ct2 = __shfl_up(vt2, 1); \
        if (FIRST) {                                                           \
            yp0 = lz ? XP[0] : cp0; yp1 = lz ? XP[0] : cp1; yp2 = lz ? XP[0] : cp2; \
            yt0 = lz ? XT[0] : ct0; yt1 = lz ? XT[0] : ct1; yt2 = lz ? XT[0] : ct2; \
        } else {                                                               \
            yp0 = lz ? sp0 : cp0; yp1 = lz ? sp1 : cp1; yp2 = lz ? sp2 : cp2;  \
            yt0 = lz ? st0 : ct0; yt1 = lz ? st1 : ct1; yt2 = lz ? st2 : ct2;  \
        }                                                                      \
    }                                                                          \
    sp0 = __shfl(vp0, 63); sp1 = __shfl(vp1, 63); sp2 = __shfl(vp2, 63);       \
    st0 = __shfl(vt0, 63); st1 = __shfl(vt1, 63); st2 = __shfl(vt2, 63);       \
    const float skip_ = (FIRST && lz) ? 0.0f : 1.0f;                           \
    _Pragma("unroll")                                                          \
    for (int j = 0; j < PER_LANE; ++j) {                                       \
        float pd0 = A0f * (XP[j] - yp0); yp0 += pd0;                           \
        float td0 = A0f * (XT[j] - yt0); yt0 += td0;                           \
        float pd1 = A1f * (XP[j] - yp1); yp1 += pd1;                           \
        float td1 = A1f * (XT[j] - yt1); yt1 += td1;                           \
        float pd2 = A2f * (XP[j] - yp2); yp2 += pd2;                           \
        float td2 = A2f * (XT[j] - yt2); yt2 += td2;                           \
        float h0 = huber(pd0, td0);                                            \
        float h1 = huber(pd1, td1);                                            \
        float h2 = huber(pd2, td2);                                            \
        if (j == 0) { h0 *= skip_; h1 *= skip_; h2 *= skip_; }                 \
        acc0 += h0; acc1 += h1; acc2 += h2;                                    \
    } }

__global__ void __launch_bounds__(256, 2) msl_main(const float* __restrict__ pred,
                                                   const float* __restrict__ targ,
                                                   float* __restrict__ out) {
    const int lane = threadIdx.x & 63;
    const int wave = threadIdx.x >> 6;
    const int row  = blockIdx.x * WPB + wave;
    const bool lz  = (lane == 0);
    const int fo   = lane * (PER_LANE / 4);   // float4 index of lane within a tile

    const float* __restrict__ prow = pred + (size_t)row * S_LEN;
    const float* __restrict__ trow = targ + (size_t)row * S_LEN;

    // EMA state at end of previous tile; loss accumulators
    float sp0 = 0.f, sp1 = 0.f, sp2 = 0.f, st0 = 0.f, st1 = 0.f, st2 = 0.f;
    float acc0 = 0.f, acc1 = 0.f, acc2 = 0.f;

    // register double buffer: load t+1 while computing t
    float xpa[PER_LANE], xta[PER_LANE], xpb[PER_LANE], xtb[PER_LANE];

    LOADT(0, xpa, xta)
    LOADT(1, xpb, xtb)
    COMPUTE(xpa, xta, 1)
    LOADT(2, xpa, xta)
    COMPUTE(xpb, xtb, 0)
    LOADT(3, xpb, xtb)
    COMPUTE(xpa, xta, 0)
    COMPUTE(xpb, xtb, 0)

    // weight the three scales, reduce wave -> block -> global atomic
    float wacc = 0.5f * acc0 + 0.3f * acc1 + 0.2f * acc2;
#pragma unroll
    for (int o = 32; o > 0; o >>= 1) wacc += __shfl_down(wacc, o);

    __shared__ float sred[WPB];
    if (lz) sred[wave] = wacc;
    __syncthreads();
    if (threadIdx.x == 0) {
        const float scale = (float)(1.0 / ((double)(S_LEN - 1) * (double)B_ROWS));
        atomicAdd(out, (sred[0] + sred[1] + sred[2] + sred[3]) * scale);
    }
}

extern "C" void kernel_launch(void* const* d_in, const int* in_sizes, int n_in,
                              void* d_out, int out_size, void* d_ws, size_t ws_size,
                              hipStream_t stream) {
    const float* pred = (const float*)d_in[0];
    const float* targ = (const float*)d_in[1];
    float* out = (float*)d_out;

    hipMemsetAsync(out, 0, sizeof(float), stream);
    msl_main<<<NBLOCKS, 256, 0, stream>>>(pred, targ, out);
}